// Round 1
// baseline (353.248 us; speedup 1.0000x reference)
//
#include <hip/hip_runtime.h>
#include <hip/hip_bf16.h>
#include <float.h>
#include <math.h>

// Problem dims (fixed by reference)
constexpr int B  = 4;
constexpr int D  = 512;
constexpr int C  = 2;
constexpr int Dc = 256;     // D / C
constexpr int F  = 256;
constexpr int T  = 256;
constexpr int FT = F * T;   // 65536
constexpr int H  = 14;
constexpr int W  = 14;
constexpr int HW = H * W;   // 196
constexpr int OUTC = 2 * Dc + D;  // 1024 output channels
constexpr float EPSV = 1e-8f;

// Workspace layout (floats):
//   xp    @ 0      : B*D   = 2048
//   maps  @ 2048   : B*2*C*HW = 3136
//   mx    @ 5184   : B*2*C = 16
//   amax  @ 5200   : 16 (int)
//   mind  @ 5216   : 8  (int)

// Kernel A: fused max-reduce over (F,T) + copy x -> out[:, 2*Dc + d]
__global__ __launch_bounds__(256) void kA_maxcopy(const float* __restrict__ x,
                                                  float* __restrict__ out,
                                                  float* __restrict__ xp) {
    const int slice = blockIdx.x;            // b*D + d
    const int b = slice / D;
    const int d = slice % D;
    const float4* xs = (const float4*)(x + (size_t)slice * FT);
    float4* os = (float4*)(out + ((size_t)(b * OUTC + 2 * Dc + d)) * FT);
    float m = -FLT_MAX;
    for (int i = threadIdx.x; i < FT / 4; i += blockDim.x) {
        float4 v = xs[i];
        os[i] = v;
        m = fmaxf(m, fmaxf(fmaxf(v.x, v.y), fmaxf(v.z, v.w)));
    }
    // wave (64) reduce then cross-wave via LDS
    for (int off = 32; off; off >>= 1) m = fmaxf(m, __shfl_down(m, off, 64));
    __shared__ float sm[4];
    const int lane = threadIdx.x & 63, wid = threadIdx.x >> 6;
    if (lane == 0) sm[wid] = m;
    __syncthreads();
    if (threadIdx.x == 0) {
        float r = sm[0];
        for (int w2 = 1; w2 < 4; ++w2) r = fmaxf(r, sm[w2]);
        xp[slice] = r;   // xp[b, c, dc] with d = c*Dc + dc
    }
}

// Kernel B: per (b,c) block — dots, norms, maps, per-(b,p,c) max/argmax
__global__ __launch_bounds__(256) void kB_maps(const float* __restrict__ v0,
                                               const float* __restrict__ v1,
                                               const float* __restrict__ xp,
                                               float* __restrict__ maps,
                                               float* __restrict__ mx,
                                               int* __restrict__ amax) {
    const int bc = blockIdx.x;
    const int b = bc / C, c = bc % C;
    const int tid = threadIdx.x;          // blockDim.x == 256 == Dc

    __shared__ float sxc[Dc], sxo[Dc];
    sxc[tid] = xp[(b * C + c) * Dc + tid];         // xp[b, c, :]
    sxo[tid] = xp[(b * C + (1 - c)) * Dc + tid];   // xp[b, 1-c, :]
    __syncthreads();

    // squared-norm reductions of both vectors
    float ec = sxc[tid] * sxc[tid];
    float eo = sxo[tid] * sxo[tid];
    for (int off = 32; off; off >>= 1) {
        ec += __shfl_down(ec, off, 64);
        eo += __shfl_down(eo, off, 64);
    }
    __shared__ float red[8];
    const int lane = tid & 63, wid = tid >> 6;
    if (lane == 0) { red[wid] = ec; red[4 + wid] = eo; }
    __syncthreads();
    __shared__ float s_xn_c, s_xn_o;
    if (tid == 0) {
        s_xn_c = sqrtf(red[0] + red[1] + red[2] + red[3]);  // xn[b,0,c]
        s_xn_o = sqrtf(red[4] + red[5] + red[6] + red[7]);  // xn[b,1,c]
    }
    __syncthreads();
    const float xn_c = s_xn_c, xn_o = s_xn_o;

    // per-hw dot products and map values
    float map0 = -FLT_MAX, map1 = -FLT_MAX;
    if (tid < HW) {
        const float* vv = (c == 0 ? v0 : v1) + (size_t)b * Dc * HW;
        float d0 = 0.f, d1 = 0.f, vs = 0.f;
        for (int dc = 0; dc < Dc; ++dc) {
            float v = vv[dc * HW + tid];
            d0 = fmaf(sxc[dc], v, d0);
            d1 = fmaf(sxo[dc], v, d1);
            vs = fmaf(v, v, vs);
        }
        float vn = sqrtf(vs);
        map0 = d0 / fmaxf(xn_c * vn, EPSV);
        map1 = d1 / fmaxf(xn_o * vn, EPSV);
        maps[((b * 2 + 0) * C + c) * HW + tid] = map0;
        maps[((b * 2 + 1) * C + c) * HW + tid] = map1;
    }

    // max + first-occurrence argmax over hw, for p=0 then p=1
    __shared__ float rv[256];
    __shared__ int ri[256];
    for (int p = 0; p < 2; ++p) {
        __syncthreads();
        rv[tid] = (tid < HW) ? (p == 0 ? map0 : map1) : -FLT_MAX;
        ri[tid] = tid;
        __syncthreads();
        for (int s = 128; s; s >>= 1) {
            if (tid < s) {
                float v2 = rv[tid + s]; int i2 = ri[tid + s];
                if (v2 > rv[tid] || (v2 == rv[tid] && i2 < ri[tid])) {
                    rv[tid] = v2; ri[tid] = i2;
                }
            }
            __syncthreads();
        }
        if (tid == 0) {
            mx[(b * 2 + p) * C + c] = rv[0];
            amax[(b * 2 + p) * C + c] = ri[0];
        }
    }
}

// Kernel C: scores, order, match_loss, att_maps, max_ind
__global__ __launch_bounds__(256) void kC_select(const float* __restrict__ maps,
                                                 const float* __restrict__ mx,
                                                 const int* __restrict__ amax,
                                                 float* __restrict__ out,
                                                 int* __restrict__ mind) {
    __shared__ int pbest[B];
    const int tid = threadIdx.x;
    if (tid == 0) {
        float L = 0.f;
        for (int b = 0; b < B; ++b) {
            float s0 = mx[(b * 2 + 0) * C + 0] + mx[(b * 2 + 0) * C + 1];
            float s1 = mx[(b * 2 + 1) * C + 0] + mx[(b * 2 + 1) * C + 1];
            // stable argsort(-scores): tie -> p=0 first
            int p = (s1 > s0) ? 1 : 0;
            pbest[b] = p;
            float ss0 = p ? s1 : s0;   // best
            float ss1 = p ? s0 : s1;   // other
            L += (ss1 - ss0);
        }
        out[(size_t)B * OUTC * FT] = L / (float)B;  // match_loss
    }
    __syncthreads();
    // att_maps: B*C*HW floats right after the loss scalar
    const size_t att_off = (size_t)B * OUTC * FT + 1;
    for (int i = tid; i < B * C * HW; i += blockDim.x) {
        int b = i / (C * HW);
        int r = i % (C * HW);
        int c = r / HW;
        int hw = r % HW;
        out[att_off + i] = maps[((b * 2 + pbest[b]) * C + c) * HW + hw];
    }
    if (tid < B * C) {
        int b = tid / C, c = tid % C;
        mind[tid] = amax[(b * 2 + pbest[b]) * C + c];
    }
}

// Kernel D: broadcast-fill out[:, 0:2*Dc] with selected v values
__global__ __launch_bounds__(256) void kD_fill(const float* __restrict__ v0,
                                               const float* __restrict__ v1,
                                               const int* __restrict__ mind,
                                               float* __restrict__ out) {
    const int n = blockIdx.x;               // b*(2*Dc) + c*Dc + dc
    const int b = n / (2 * Dc);
    const int r = n % (2 * Dc);
    const int c = r / Dc;
    const int dc = r % Dc;
    const int hw = mind[b * C + c];
    const float* vv = (c == 0 ? v0 : v1);
    const float val = vv[((size_t)(b * Dc + dc)) * HW + hw];
    const float4 v4 = make_float4(val, val, val, val);
    float4* os = (float4*)(out + ((size_t)(b * OUTC + c * Dc + dc)) * FT);
    for (int i = threadIdx.x; i < FT / 4; i += blockDim.x) os[i] = v4;
}

extern "C" void kernel_launch(void* const* d_in, const int* in_sizes, int n_in,
                              void* d_out, int out_size, void* d_ws, size_t ws_size,
                              hipStream_t stream) {
    const float* x  = (const float*)d_in[0];
    const float* v0 = (const float*)d_in[1];
    const float* v1 = (const float*)d_in[2];
    float* out = (float*)d_out;
    float* ws = (float*)d_ws;

    float* xp   = ws;                 // 2048
    float* maps = ws + 2048;          // 3136
    float* mx   = ws + 5184;          // 16
    int*   amax = (int*)(ws + 5200);  // 16
    int*   mind = (int*)(ws + 5216);  // 8

    kA_maxcopy<<<B * D, 256, 0, stream>>>(x, out, xp);
    kB_maps<<<B * C, 256, 0, stream>>>(v0, v1, xp, maps, mx, amax);
    kC_select<<<1, 256, 0, stream>>>(maps, mx, amax, out, mind);
    kD_fill<<<B * 2 * Dc, 256, 0, stream>>>(v0, v1, mind, out);
}

// Round 2
// 304.038 us; speedup vs baseline: 1.1619x; 1.1619x over previous
//
#include <hip/hip_runtime.h>
#include <hip/hip_bf16.h>
#include <float.h>
#include <math.h>

// Problem dims (fixed by reference)
constexpr int B  = 4;
constexpr int D  = 512;
constexpr int C  = 2;
constexpr int Dc = 256;     // D / C
constexpr int F  = 256;
constexpr int T  = 256;
constexpr int FT = F * T;   // 65536
constexpr int H  = 14;
constexpr int W  = 14;
constexpr int HW = H * W;   // 196
constexpr int OUTC = 2 * Dc + D;  // 1024 output channels
constexpr float EPSV = 1e-8f;

typedef float f4 __attribute__((ext_vector_type(4)));

// Workspace layout (floats):
//   xp    @ 0      : B*D   = 2048
//   maps  @ 2048   : B*2*C*HW = 3136
//   mx    @ 5184   : B*2*C = 16
//   amax  @ 5200   : 16 (int)
//   mind  @ 5216   : 8  (int)

// Kernel A: fused max-reduce over (F,T) + copy x -> out[:, 2*Dc + d]
// Unrolled x8 for MLP; nontemporal (streaming) loads/stores — data never reused.
__global__ __launch_bounds__(256) void kA_maxcopy(const float* __restrict__ x,
                                                  float* __restrict__ out,
                                                  float* __restrict__ xp) {
    const int slice = blockIdx.x;            // b*D + d
    const int b = slice / D;
    const int d = slice % D;
    const f4* xs = (const f4*)(x + (size_t)slice * FT);
    f4* os = (f4*)(out + ((size_t)(b * OUTC + 2 * Dc + d)) * FT);
    float m = -FLT_MAX;
    // FT/4 = 16384 f4 elements; 256 threads x 8-deep unroll x 8 outer iters
    for (int i0 = threadIdx.x; i0 < FT / 4; i0 += 256 * 8) {
        f4 v[8];
        #pragma unroll
        for (int u = 0; u < 8; ++u)
            v[u] = __builtin_nontemporal_load(&xs[i0 + u * 256]);
        #pragma unroll
        for (int u = 0; u < 8; ++u) {
            __builtin_nontemporal_store(v[u], &os[i0 + u * 256]);
            m = fmaxf(m, fmaxf(fmaxf(v[u].x, v[u].y), fmaxf(v[u].z, v[u].w)));
        }
    }
    // wave (64) reduce then cross-wave via LDS
    for (int off = 32; off; off >>= 1) m = fmaxf(m, __shfl_down(m, off, 64));
    __shared__ float sm[4];
    const int lane = threadIdx.x & 63, wid = threadIdx.x >> 6;
    if (lane == 0) sm[wid] = m;
    __syncthreads();
    if (threadIdx.x == 0) {
        float r = sm[0];
        for (int w2 = 1; w2 < 4; ++w2) r = fmaxf(r, sm[w2]);
        xp[slice] = r;   // xp[b, c, dc] with d = c*Dc + dc
    }
}

// Kernel B: per (b,c) block — dots, norms, maps, per-(b,p,c) max/argmax
__global__ __launch_bounds__(256) void kB_maps(const float* __restrict__ v0,
                                               const float* __restrict__ v1,
                                               const float* __restrict__ xp,
                                               float* __restrict__ maps,
                                               float* __restrict__ mx,
                                               int* __restrict__ amax) {
    const int bc = blockIdx.x;
    const int b = bc / C, c = bc % C;
    const int tid = threadIdx.x;          // blockDim.x == 256 == Dc

    __shared__ float sxc[Dc], sxo[Dc];
    sxc[tid] = xp[(b * C + c) * Dc + tid];         // xp[b, c, :]
    sxo[tid] = xp[(b * C + (1 - c)) * Dc + tid];   // xp[b, 1-c, :]
    __syncthreads();

    // squared-norm reductions of both vectors
    float ec = sxc[tid] * sxc[tid];
    float eo = sxo[tid] * sxo[tid];
    for (int off = 32; off; off >>= 1) {
        ec += __shfl_down(ec, off, 64);
        eo += __shfl_down(eo, off, 64);
    }
    __shared__ float red[8];
    const int lane = tid & 63, wid = tid >> 6;
    if (lane == 0) { red[wid] = ec; red[4 + wid] = eo; }
    __syncthreads();
    __shared__ float s_xn_c, s_xn_o;
    if (tid == 0) {
        s_xn_c = sqrtf(red[0] + red[1] + red[2] + red[3]);  // xn[b,0,c]
        s_xn_o = sqrtf(red[4] + red[5] + red[6] + red[7]);  // xn[b,1,c]
    }
    __syncthreads();
    const float xn_c = s_xn_c, xn_o = s_xn_o;

    // per-hw dot products and map values
    float map0 = -FLT_MAX, map1 = -FLT_MAX;
    if (tid < HW) {
        const float* vv = (c == 0 ? v0 : v1) + (size_t)b * Dc * HW;
        float d0 = 0.f, d1 = 0.f, vs = 0.f;
        for (int dc = 0; dc < Dc; ++dc) {
            float v = vv[dc * HW + tid];
            d0 = fmaf(sxc[dc], v, d0);
            d1 = fmaf(sxo[dc], v, d1);
            vs = fmaf(v, v, vs);
        }
        float vn = sqrtf(vs);
        map0 = d0 / fmaxf(xn_c * vn, EPSV);
        map1 = d1 / fmaxf(xn_o * vn, EPSV);
        maps[((b * 2 + 0) * C + c) * HW + tid] = map0;
        maps[((b * 2 + 1) * C + c) * HW + tid] = map1;
    }

    // max + first-occurrence argmax over hw, for p=0 then p=1
    __shared__ float rv[256];
    __shared__ int ri[256];
    for (int p = 0; p < 2; ++p) {
        __syncthreads();
        rv[tid] = (tid < HW) ? (p == 0 ? map0 : map1) : -FLT_MAX;
        ri[tid] = tid;
        __syncthreads();
        for (int s = 128; s; s >>= 1) {
            if (tid < s) {
                float v2 = rv[tid + s]; int i2 = ri[tid + s];
                if (v2 > rv[tid] || (v2 == rv[tid] && i2 < ri[tid])) {
                    rv[tid] = v2; ri[tid] = i2;
                }
            }
            __syncthreads();
        }
        if (tid == 0) {
            mx[(b * 2 + p) * C + c] = rv[0];
            amax[(b * 2 + p) * C + c] = ri[0];
        }
    }
}

// Kernel C: scores, order, match_loss, att_maps, max_ind
__global__ __launch_bounds__(256) void kC_select(const float* __restrict__ maps,
                                                 const float* __restrict__ mx,
                                                 const int* __restrict__ amax,
                                                 float* __restrict__ out,
                                                 int* __restrict__ mind) {
    __shared__ int pbest[B];
    const int tid = threadIdx.x;
    if (tid == 0) {
        float L = 0.f;
        for (int b = 0; b < B; ++b) {
            float s0 = mx[(b * 2 + 0) * C + 0] + mx[(b * 2 + 0) * C + 1];
            float s1 = mx[(b * 2 + 1) * C + 0] + mx[(b * 2 + 1) * C + 1];
            // stable argsort(-scores): tie -> p=0 first
            int p = (s1 > s0) ? 1 : 0;
            pbest[b] = p;
            float ss0 = p ? s1 : s0;   // best
            float ss1 = p ? s0 : s1;   // other
            L += (ss1 - ss0);
        }
        out[(size_t)B * OUTC * FT] = L / (float)B;  // match_loss
    }
    __syncthreads();
    // att_maps: B*C*HW floats right after the loss scalar
    const size_t att_off = (size_t)B * OUTC * FT + 1;
    for (int i = tid; i < B * C * HW; i += blockDim.x) {
        int b = i / (C * HW);
        int r = i % (C * HW);
        int c = r / HW;
        int hw = r % HW;
        out[att_off + i] = maps[((b * 2 + pbest[b]) * C + c) * HW + hw];
    }
    if (tid < B * C) {
        int b = tid / C, c = tid % C;
        mind[tid] = amax[(b * 2 + pbest[b]) * C + c];
    }
}

// Kernel D: broadcast-fill out[:, 0:2*Dc] with selected v values
__global__ __launch_bounds__(256) void kD_fill(const float* __restrict__ v0,
                                               const float* __restrict__ v1,
                                               const int* __restrict__ mind,
                                               float* __restrict__ out) {
    const int n = blockIdx.x;               // b*(2*Dc) + c*Dc + dc
    const int b = n / (2 * Dc);
    const int r = n % (2 * Dc);
    const int c = r / Dc;
    const int dc = r % Dc;
    const int hw = mind[b * C + c];
    const float* vv = (c == 0 ? v0 : v1);
    const float val = vv[((size_t)(b * Dc + dc)) * HW + hw];
    f4 v4 = {val, val, val, val};
    f4* os = (f4*)(out + ((size_t)(b * OUTC + c * Dc + dc)) * FT);
    for (int i0 = threadIdx.x; i0 < FT / 4; i0 += 256 * 8) {
        #pragma unroll
        for (int u = 0; u < 8; ++u)
            __builtin_nontemporal_store(v4, &os[i0 + u * 256]);
    }
}

extern "C" void kernel_launch(void* const* d_in, const int* in_sizes, int n_in,
                              void* d_out, int out_size, void* d_ws, size_t ws_size,
                              hipStream_t stream) {
    const float* x  = (const float*)d_in[0];
    const float* v0 = (const float*)d_in[1];
    const float* v1 = (const float*)d_in[2];
    float* out = (float*)d_out;
    float* ws = (float*)d_ws;

    float* xp   = ws;                 // 2048
    float* maps = ws + 2048;          // 3136
    float* mx   = ws + 5184;          // 16
    int*   amax = (int*)(ws + 5200);  // 16
    int*   mind = (int*)(ws + 5216);  // 8

    kA_maxcopy<<<B * D, 256, 0, stream>>>(x, out, xp);
    kB_maps<<<B * C, 256, 0, stream>>>(v0, v1, xp, maps, mx, amax);
    kC_select<<<1, 256, 0, stream>>>(maps, mx, amax, out, mind);
    kD_fill<<<B * 2 * Dc, 256, 0, stream>>>(v0, v1, mind, out);
}